// Round 1
// baseline (853.461 us; speedup 1.0000x reference)
//
#include <hip/hip_runtime.h>
#include <hip/hip_bf16.h>

#define N_NODES 50000
#define N_EDGES 1600000
#define IN_DIM 1024
#define HID 128

// ---------------------------------------------------------------- init
__global__ void init_kernel(int* __restrict__ deg, float* __restrict__ out, int out_n) {
    int i = blockIdx.x * 256 + threadIdx.x;
    if (i < N_NODES) deg[i] = 0;
    if (i < out_n) out[i] = 0.0f;
}

// ---------------------------------------------------------------- GEMM h = x @ W
// BM=64 rows/block, BN=128 (full), BK=32. 256 threads: tx=t&31 -> cols tx*4..+3,
// ty=t>>5 -> rows ty*8..+7. fp32 vector FMA (no fp32 MFMA on CDNA4).
#define BM 64
#define BK 32
__global__ __launch_bounds__(256) void gemm_kernel(const float* __restrict__ x,
                                                   const float* __restrict__ W,
                                                   float* __restrict__ h) {
    __shared__ alignas(16) float xs[BK][BM + 4];   // x tile transposed: xs[k][row]
    __shared__ alignas(16) float ws[BK][HID];
    const int t  = threadIdx.x;
    const int tx = t & 31, ty = t >> 5;
    const int m0 = blockIdx.x * BM;
    float acc[8][4] = {};
    for (int k0 = 0; k0 < IN_DIM; k0 += BK) {
        // stage x tile (64 rows x 32 k): 512 float4 loads, transpose into LDS
#pragma unroll
        for (int l = 0; l < 2; ++l) {
            int f   = t + l * 256;
            int row = f >> 3;          // 0..63
            int kq  = f & 7;           // 0..7 -> k = kq*4..+3
            int gr  = m0 + row;
            float4 v = make_float4(0.f, 0.f, 0.f, 0.f);
            if (gr < N_NODES)
                v = *(const float4*)(x + (size_t)gr * IN_DIM + k0 + kq * 4);
            xs[kq * 4 + 0][row] = v.x;
            xs[kq * 4 + 1][row] = v.y;
            xs[kq * 4 + 2][row] = v.z;
            xs[kq * 4 + 3][row] = v.w;
        }
        // stage W tile (32 k x 128 cols): 1024 float4 loads
#pragma unroll
        for (int l = 0; l < 4; ++l) {
            int f  = t + l * 256;
            int kr = f >> 5;           // 0..31
            int cq = f & 31;           // col = cq*4
            *(float4*)(&ws[kr][cq * 4]) =
                *(const float4*)(W + (size_t)(k0 + kr) * HID + cq * 4);
        }
        __syncthreads();
#pragma unroll 4
        for (int kk = 0; kk < BK; ++kk) {
            float4 a0 = *(const float4*)(&xs[kk][ty * 8]);
            float4 a1 = *(const float4*)(&xs[kk][ty * 8 + 4]);
            float4 b  = *(const float4*)(&ws[kk][tx * 4]);
            float a[8] = {a0.x, a0.y, a0.z, a0.w, a1.x, a1.y, a1.z, a1.w};
            float bb[4] = {b.x, b.y, b.z, b.w};
#pragma unroll
            for (int i = 0; i < 8; ++i)
#pragma unroll
                for (int j = 0; j < 4; ++j)
                    acc[i][j] = fmaf(a[i], bb[j], acc[i][j]);
        }
        __syncthreads();
    }
#pragma unroll
    for (int i = 0; i < 8; ++i) {
        int row = m0 + ty * 8 + i;
        if (row < N_NODES) {
            float4 v = make_float4(acc[i][0], acc[i][1], acc[i][2], acc[i][3]);
            *(float4*)(h + (size_t)row * HID + tx * 4) = v;
        }
    }
}

// ---------------------------------------------------------------- a_src/a_dst = h . att
__global__ void att_kernel(const float* __restrict__ h, const float* __restrict__ as,
                           const float* __restrict__ adv, float* __restrict__ o_s,
                           float* __restrict__ o_d) {
    int wid = threadIdx.x >> 6, lane = threadIdx.x & 63;
    int i = blockIdx.x * 4 + wid;
    if (i >= N_NODES) return;
    float h0 = h[(size_t)i * HID + lane];
    float h1 = h[(size_t)i * HID + 64 + lane];
    float ps = h0 * as[lane] + h1 * as[64 + lane];
    float pd = h0 * adv[lane] + h1 * adv[64 + lane];
    for (int o = 32; o; o >>= 1) {
        ps += __shfl_xor(ps, o);
        pd += __shfl_xor(pd, o);
    }
    if (lane == 0) { o_s[i] = ps; o_d[i] = pd; }
}

// ---------------------------------------------------------------- CSR build
__global__ void hist_kernel(const int* __restrict__ ei, int* __restrict__ deg) {
    int e = blockIdx.x * 256 + threadIdx.x;
    if (e < N_EDGES) atomicAdd(&deg[ei[N_EDGES + e]], 1);
}

// 1024 elems/block, 256 threads x 4
__global__ void scan1_kernel(const int* __restrict__ deg, int* __restrict__ bsum) {
    int b = blockIdx.x, t = threadIdx.x;
    int base = b * 1024 + t * 4;
    int s = 0;
#pragma unroll
    for (int j = 0; j < 4; ++j) {
        int idx = base + j;
        if (idx < N_NODES) s += deg[idx];
    }
    for (int o = 32; o; o >>= 1) s += __shfl_xor(s, o);
    __shared__ int wsum[4];
    int lane = t & 63, w = t >> 6;
    if (lane == 0) wsum[w] = s;
    __syncthreads();
    if (t == 0) bsum[b] = wsum[0] + wsum[1] + wsum[2] + wsum[3];
}

__global__ void scan2_kernel(const int* __restrict__ bsum, int* __restrict__ boff,
                             int* __restrict__ rowstart, int nb) {
    if (threadIdx.x == 0 && blockIdx.x == 0) {
        int run = 0;
        for (int i = 0; i < nb; ++i) { boff[i] = run; run += bsum[i]; }
        rowstart[N_NODES] = run;
    }
}

__global__ void scan3_kernel(int* __restrict__ deg, const int* __restrict__ boff,
                             int* __restrict__ rowstart) {
    int b = blockIdx.x, t = threadIdx.x;
    int base = b * 1024 + t * 4;
    int v[4]; int s = 0;
#pragma unroll
    for (int j = 0; j < 4; ++j) {
        int idx = base + j;
        v[j] = (idx < N_NODES) ? deg[idx] : 0;
        s += v[j];
    }
    int lane = t & 63, w = t >> 6;
    int inc = s;
    for (int o = 1; o < 64; o <<= 1) {
        int u = __shfl_up(inc, o);
        if (lane >= o) inc += u;
    }
    __shared__ int wt[4];
    if (lane == 63) wt[w] = inc;
    __syncthreads();
    int woff = 0;
    for (int i = 0; i < w; ++i) woff += wt[i];
    int run = woff + inc - s + boff[b];
#pragma unroll
    for (int j = 0; j < 4; ++j) {
        int idx = base + j;
        if (idx < N_NODES) {
            rowstart[idx] = run;
            run += v[j];
            deg[idx] = 0;   // re-zero: reused as scatter cursor
        }
    }
}

__global__ void scatter_kernel(const int* __restrict__ ei, const int* __restrict__ rowstart,
                               int* __restrict__ cursor, int* __restrict__ csr) {
    int e = blockIdx.x * 256 + threadIdx.x;
    if (e >= N_EDGES) return;
    int s = ei[e], d = ei[N_EDGES + e];
    int pos = atomicAdd(&cursor[d], 1);
    csr[rowstart[d] + pos] = s;
}

// ---------------------------------------------------------------- per-node softmax+aggregate+pool
// One wave per dst node. Self-loop handled implicitly. Lane owns features 2*lane, 2*lane+1.
__global__ __launch_bounds__(256) void aggregate_kernel(
    const float* __restrict__ h, const float* __restrict__ a_src,
    const float* __restrict__ a_dst, const int* __restrict__ rowstart,
    const int* __restrict__ csr, const float* __restrict__ bias,
    const int* __restrict__ batch, float* __restrict__ out) {
    int wid = threadIdx.x >> 6, lane = threadIdx.x & 63;
    int n = blockIdx.x * 4 + wid;
    if (n >= N_NODES) return;
    int rs = rowstart[n], re = rowstart[n + 1];
    float adn = a_dst[n];
    float aself = a_src[n] + adn;
    float eself = aself > 0.f ? aself : 0.2f * aself;
    // pass 1: max over edges (lane-parallel) + self-loop
    float mx = (lane == 0) ? eself : -1e30f;
    for (int j = rs + lane; j < re; j += 64) {
        float v = a_src[csr[j]] + adn;
        v = v > 0.f ? v : 0.2f * v;
        mx = fmaxf(mx, v);
    }
    for (int o = 32; o; o >>= 1) mx = fmaxf(mx, __shfl_xor(mx, o));
    // pass 2: denom + weighted feature accumulation (serial over edges, lanes own features)
    float pself = __expf(eself - mx);
    float denom = pself;
    float2 hv = *(const float2*)(h + (size_t)n * HID + 2 * lane);
    float2 acc = make_float2(pself * hv.x, pself * hv.y);
    for (int j = rs; j < re; ++j) {
        int s = csr[j];                                   // wave-uniform -> broadcast
        float v = a_src[s] + adn;
        v = v > 0.f ? v : 0.2f * v;
        float p = __expf(v - mx);
        denom += p;
        float2 hs = *(const float2*)(h + (size_t)s * HID + 2 * lane);
        acc.x = fmaf(p, hs.x, acc.x);
        acc.y = fmaf(p, hs.y, acc.y);
    }
    float inv = 1.0f / denom;
    float o0 = fmaxf(acc.x * inv + bias[2 * lane], 0.0f);
    float o1 = fmaxf(acc.y * inv + bias[2 * lane + 1], 0.0f);
    // global max pool: all values >= 0 -> uint bit-pattern atomicMax is order-correct
    int g = batch[n];
    unsigned* outp = (unsigned*)(out + (size_t)g * HID);
    atomicMax(&outp[2 * lane], __float_as_uint(o0));
    atomicMax(&outp[2 * lane + 1], __float_as_uint(o1));
}

// ---------------------------------------------------------------- launch
extern "C" void kernel_launch(void* const* d_in, const int* in_sizes, int n_in,
                              void* d_out, int out_size, void* d_ws, size_t ws_size,
                              hipStream_t stream) {
    const float* x     = (const float*)d_in[0];
    const float* W     = (const float*)d_in[1];
    const float* att_s = (const float*)d_in[2];
    const float* att_d = (const float*)d_in[3];
    const float* bias  = (const float*)d_in[4];
    const int*   ei    = (const int*)d_in[5];
    const int*   batch = (const int*)d_in[6];
    float*       out   = (float*)d_out;

    char* ws = (char*)d_ws;
    size_t off = 0;
    auto alloc = [&](size_t bytes) -> void* {
        void* p = ws + off;
        off += (bytes + 255) & ~(size_t)255;
        return p;
    };
    const int NB = (N_NODES + 1023) / 1024;   // 49
    float* h        = (float*)alloc((size_t)N_NODES * HID * 4);
    float* a_src    = (float*)alloc((size_t)N_NODES * 4);
    float* a_dst    = (float*)alloc((size_t)N_NODES * 4);
    int*   deg      = (int*)alloc((size_t)N_NODES * 4);
    int*   rowstart = (int*)alloc((size_t)(N_NODES + 1) * 4);
    int*   bsum     = (int*)alloc((size_t)NB * 4);
    int*   boff     = (int*)alloc((size_t)NB * 4);
    int*   csr      = (int*)alloc((size_t)N_EDGES * 4);
    (void)ws_size; (void)in_sizes; (void)n_in;

    int init_n = (N_NODES > out_size ? N_NODES : out_size);
    hipLaunchKernelGGL(init_kernel, dim3((init_n + 255) / 256), dim3(256), 0, stream,
                       deg, out, out_size);
    hipLaunchKernelGGL(gemm_kernel, dim3((N_NODES + BM - 1) / BM), dim3(256), 0, stream,
                       x, W, h);
    hipLaunchKernelGGL(att_kernel, dim3((N_NODES + 3) / 4), dim3(256), 0, stream,
                       h, att_s, att_d, a_src, a_dst);
    hipLaunchKernelGGL(hist_kernel, dim3((N_EDGES + 255) / 256), dim3(256), 0, stream,
                       ei, deg);
    hipLaunchKernelGGL(scan1_kernel, dim3(NB), dim3(256), 0, stream, deg, bsum);
    hipLaunchKernelGGL(scan2_kernel, dim3(1), dim3(64), 0, stream, bsum, boff, rowstart, NB);
    hipLaunchKernelGGL(scan3_kernel, dim3(NB), dim3(256), 0, stream, deg, boff, rowstart);
    hipLaunchKernelGGL(scatter_kernel, dim3((N_EDGES + 255) / 256), dim3(256), 0, stream,
                       ei, rowstart, deg, csr);
    hipLaunchKernelGGL(aggregate_kernel, dim3((N_NODES + 3) / 4), dim3(256), 0, stream,
                       h, a_src, a_dst, rowstart, csr, bias, batch, out);
}

// Round 2
// 729.731 us; speedup vs baseline: 1.1696x; 1.1696x over previous
//
#include <hip/hip_runtime.h>
#include <hip/hip_bf16.h>

#define N_NODES 50000
#define N_EDGES 1600000
#define IN_DIM 1024
#define HID 128

typedef __bf16 bf16x8 __attribute__((ext_vector_type(8)));
typedef float f32x4 __attribute__((ext_vector_type(4)));
typedef __bf16 bf16x4 __attribute__((ext_vector_type(4)));

// ---------------------------------------------------------------- init
__global__ void init_kernel(int* __restrict__ deg, float* __restrict__ out, int out_n) {
    int i = blockIdx.x * 256 + threadIdx.x;
    if (i < N_NODES) deg[i] = 0;
    if (i < out_n) out[i] = 0.0f;
}

// ---------------------------------------------------------------- W^T -> bf16  (wt[n][k], 128x1024)
__global__ void wtrans_kernel(const float* __restrict__ W, __bf16* __restrict__ wt) {
    int i = blockIdx.x * 256 + threadIdx.x;      // over 128*1024
    int n = i >> 10, k = i & 1023;
    wt[i] = (__bf16)W[(size_t)k * HID + n];
}

// ---------------------------------------------------------------- GEMM h = x @ W (bf16 MFMA)
// 128 rows/block x 128 cols (full HID). 4 waves, each 32 rows. BK=32, 16x16x32 bf16 MFMA.
// LDS rows padded to 40 bf16 (80 B): frag-read bank starts (m*20)%32 -> 2-way (free).
__global__ __launch_bounds__(256) void gemm_kernel(const float* __restrict__ x,
                                                   const __bf16* __restrict__ wt,
                                                   float* __restrict__ h) {
    __shared__ __bf16 xa[128][40];
    __shared__ __bf16 wb[128][40];
    const int t = threadIdx.x;
    const int m0 = blockIdx.x * 128;
    const int wid = t >> 6, lane = t & 63;
    const int lm = lane & 15, q8 = (lane >> 4) * 8;
    const int rw0 = wid * 32;

    f32x4 acc[2][8] = {};
    for (int k0 = 0; k0 < IN_DIM; k0 += 32) {
        // stage x tile: 128 rows x 32 k fp32 -> bf16. 1024 float4 loads (4/thread).
#pragma unroll
        for (int l = 0; l < 4; ++l) {
            int f = t + l * 256;
            int row = f >> 3, kq = f & 7;       // kq -> k = kq*4
            int gr = m0 + row;
            float4 v = make_float4(0.f, 0.f, 0.f, 0.f);
            if (gr < N_NODES)
                v = *(const float4*)(x + (size_t)gr * IN_DIM + k0 + kq * 4);
            bf16x4 b; b[0] = (__bf16)v.x; b[1] = (__bf16)v.y; b[2] = (__bf16)v.z; b[3] = (__bf16)v.w;
            *(bf16x4*)&xa[row][kq * 4] = b;     // 8B store, aligned (80B row stride)
        }
        // stage W^T tile: 128 n x 32 k bf16. 1024 8B loads (4/thread).
#pragma unroll
        for (int l = 0; l < 4; ++l) {
            int f = t + l * 256;
            int n = f >> 3, c = f & 7;          // c -> k = c*4
            *(uint2*)&wb[n][c * 4] = *(const uint2*)(wt + (size_t)n * IN_DIM + k0 + c * 4);
        }
        __syncthreads();
        // fragments + MFMA
        bf16x8 af0 = *(const bf16x8*)&xa[rw0 + lm][q8];
        bf16x8 af1 = *(const bf16x8*)&xa[rw0 + 16 + lm][q8];
#pragma unroll
        for (int ct = 0; ct < 8; ++ct) {
            bf16x8 bfr = *(const bf16x8*)&wb[ct * 16 + lm][q8];
            acc[0][ct] = __builtin_amdgcn_mfma_f32_16x16x32_bf16(af0, bfr, acc[0][ct], 0, 0, 0);
            acc[1][ct] = __builtin_amdgcn_mfma_f32_16x16x32_bf16(af1, bfr, acc[1][ct], 0, 0, 0);
        }
        __syncthreads();
    }
    // epilogue: C/D layout col=lane&15, row=(lane>>4)*4+reg
    const int quad = lane >> 4;
#pragma unroll
    for (int rt = 0; rt < 2; ++rt) {
#pragma unroll
        for (int reg = 0; reg < 4; ++reg) {
            int row = m0 + rw0 + rt * 16 + quad * 4 + reg;
            if (row < N_NODES) {
#pragma unroll
                for (int ct = 0; ct < 8; ++ct)
                    h[(size_t)row * HID + ct * 16 + lm] = acc[rt][ct][reg];
            }
        }
    }
}

// ---------------------------------------------------------------- a_src/a_dst = h . att
__global__ void att_kernel(const float* __restrict__ h, const float* __restrict__ as,
                           const float* __restrict__ adv, float* __restrict__ o_s,
                           float* __restrict__ o_d) {
    int wid = threadIdx.x >> 6, lane = threadIdx.x & 63;
    int i = blockIdx.x * 4 + wid;
    if (i >= N_NODES) return;
    float h0 = h[(size_t)i * HID + lane];
    float h1 = h[(size_t)i * HID + 64 + lane];
    float ps = h0 * as[lane] + h1 * as[64 + lane];
    float pd = h0 * adv[lane] + h1 * adv[64 + lane];
    for (int o = 32; o; o >>= 1) {
        ps += __shfl_xor(ps, o);
        pd += __shfl_xor(pd, o);
    }
    if (lane == 0) { o_s[i] = ps; o_d[i] = pd; }
}

// ---------------------------------------------------------------- CSR build
__global__ void hist_kernel(const int* __restrict__ ei, int* __restrict__ deg) {
    int e = blockIdx.x * 256 + threadIdx.x;
    if (e < N_EDGES) atomicAdd(&deg[ei[N_EDGES + e]], 1);
}

__global__ void scan1_kernel(const int* __restrict__ deg, int* __restrict__ bsum) {
    int b = blockIdx.x, t = threadIdx.x;
    int base = b * 1024 + t * 4;
    int s = 0;
#pragma unroll
    for (int j = 0; j < 4; ++j) {
        int idx = base + j;
        if (idx < N_NODES) s += deg[idx];
    }
    for (int o = 32; o; o >>= 1) s += __shfl_xor(s, o);
    __shared__ int wsum[4];
    int lane = t & 63, w = t >> 6;
    if (lane == 0) wsum[w] = s;
    __syncthreads();
    if (t == 0) bsum[b] = wsum[0] + wsum[1] + wsum[2] + wsum[3];
}

__global__ void scan2_kernel(const int* __restrict__ bsum, int* __restrict__ boff,
                             int* __restrict__ rowstart, int nb) {
    if (threadIdx.x == 0 && blockIdx.x == 0) {
        int run = 0;
        for (int i = 0; i < nb; ++i) { boff[i] = run; run += bsum[i]; }
        rowstart[N_NODES] = run;
    }
}

__global__ void scan3_kernel(int* __restrict__ deg, const int* __restrict__ boff,
                             int* __restrict__ rowstart) {
    int b = blockIdx.x, t = threadIdx.x;
    int base = b * 1024 + t * 4;
    int v[4]; int s = 0;
#pragma unroll
    for (int j = 0; j < 4; ++j) {
        int idx = base + j;
        v[j] = (idx < N_NODES) ? deg[idx] : 0;
        s += v[j];
    }
    int lane = t & 63, w = t >> 6;
    int inc = s;
    for (int o = 1; o < 64; o <<= 1) {
        int u = __shfl_up(inc, o);
        if (lane >= o) inc += u;
    }
    __shared__ int wt[4];
    if (lane == 63) wt[w] = inc;
    __syncthreads();
    int woff = 0;
    for (int i = 0; i < w; ++i) woff += wt[i];
    int run = woff + inc - s + boff[b];
#pragma unroll
    for (int j = 0; j < 4; ++j) {
        int idx = base + j;
        if (idx < N_NODES) {
            rowstart[idx] = run;
            run += v[j];
            deg[idx] = 0;   // re-zero: reused as scatter cursor
        }
    }
}

__global__ void scatter_kernel(const int* __restrict__ ei, const int* __restrict__ rowstart,
                               int* __restrict__ cursor, int* __restrict__ csr) {
    int e = blockIdx.x * 256 + threadIdx.x;
    if (e >= N_EDGES) return;
    int s = ei[e], d = ei[N_EDGES + e];
    int pos = atomicAdd(&cursor[d], 1);
    csr[rowstart[d] + pos] = s;
}

// ---------------------------------------------------------------- softmax+aggregate+pool
// One wave per dst node, lane owns features {2*lane, 2*lane+1}. No max-subtraction:
// logits bounded (|e| < ~4), exp is fp32-safe; alpha = p/denom identical in exact math.
// Edge loop unrolled x8 for memory-level parallelism (8 independent 512B gathers in flight).
__device__ __forceinline__ float lrelu(float v) { return v > 0.f ? v : 0.2f * v; }

__global__ __launch_bounds__(256) void aggregate_kernel(
    const float* __restrict__ h, const float* __restrict__ a_src,
    const float* __restrict__ a_dst, const int* __restrict__ rowstart,
    const int* __restrict__ csr, const float* __restrict__ bias,
    const int* __restrict__ batch, float* __restrict__ out) {
    int wid = threadIdx.x >> 6, lane = threadIdx.x & 63;
    int n = blockIdx.x * 4 + wid;
    if (n >= N_NODES) return;
    int rs = rowstart[n], re = rowstart[n + 1];
    float adn = a_dst[n];
    float pself = __expf(lrelu(a_src[n] + adn));
    float2 hv = *(const float2*)(h + (size_t)n * HID + 2 * lane);
    float denom = pself;
    float2 acc = make_float2(pself * hv.x, pself * hv.y);
    int j = rs;
    for (; j + 8 <= re; j += 8) {
        int s[8];
#pragma unroll
        for (int i = 0; i < 8; ++i) s[i] = csr[j + i];
        float a[8];
#pragma unroll
        for (int i = 0; i < 8; ++i) a[i] = a_src[s[i]];
        float2 g[8];
#pragma unroll
        for (int i = 0; i < 8; ++i) g[i] = *(const float2*)(h + (size_t)s[i] * HID + 2 * lane);
#pragma unroll
        for (int i = 0; i < 8; ++i) {
            float p = __expf(lrelu(a[i] + adn));
            denom += p;
            acc.x = fmaf(p, g[i].x, acc.x);
            acc.y = fmaf(p, g[i].y, acc.y);
        }
    }
    for (; j < re; ++j) {
        int s = csr[j];
        float p = __expf(lrelu(a_src[s] + adn));
        float2 g = *(const float2*)(h + (size_t)s * HID + 2 * lane);
        denom += p;
        acc.x = fmaf(p, g.x, acc.x);
        acc.y = fmaf(p, g.y, acc.y);
    }
    float inv = 1.0f / denom;
    float o0 = fmaxf(acc.x * inv + bias[2 * lane], 0.0f);
    float o1 = fmaxf(acc.y * inv + bias[2 * lane + 1], 0.0f);
    int g = batch[n];
    unsigned* outp = (unsigned*)(out + (size_t)g * HID);
    atomicMax(&outp[2 * lane], __float_as_uint(o0));
    atomicMax(&outp[2 * lane + 1], __float_as_uint(o1));
}

// ---------------------------------------------------------------- launch
extern "C" void kernel_launch(void* const* d_in, const int* in_sizes, int n_in,
                              void* d_out, int out_size, void* d_ws, size_t ws_size,
                              hipStream_t stream) {
    const float* x     = (const float*)d_in[0];
    const float* W     = (const float*)d_in[1];
    const float* att_s = (const float*)d_in[2];
    const float* att_d = (const float*)d_in[3];
    const float* bias  = (const float*)d_in[4];
    const int*   ei    = (const int*)d_in[5];
    const int*   batch = (const int*)d_in[6];
    float*       out   = (float*)d_out;

    char* ws = (char*)d_ws;
    size_t off = 0;
    auto alloc = [&](size_t bytes) -> void* {
        void* p = ws + off;
        off += (bytes + 255) & ~(size_t)255;
        return p;
    };
    const int NB = (N_NODES + 1023) / 1024;   // 49
    float*  h        = (float*)alloc((size_t)N_NODES * HID * 4);
    __bf16* wt       = (__bf16*)alloc((size_t)HID * IN_DIM * 2);
    float*  a_src    = (float*)alloc((size_t)N_NODES * 4);
    float*  a_dst    = (float*)alloc((size_t)N_NODES * 4);
    int*    deg      = (int*)alloc((size_t)N_NODES * 4);
    int*    rowstart = (int*)alloc((size_t)(N_NODES + 1) * 4);
    int*    bsum     = (int*)alloc((size_t)NB * 4);
    int*    boff     = (int*)alloc((size_t)NB * 4);
    int*    csr      = (int*)alloc((size_t)N_EDGES * 4);
    (void)ws_size; (void)in_sizes; (void)n_in;

    int init_n = (N_NODES > out_size ? N_NODES : out_size);
    hipLaunchKernelGGL(init_kernel, dim3((init_n + 255) / 256), dim3(256), 0, stream,
                       deg, out, out_size);
    hipLaunchKernelGGL(wtrans_kernel, dim3((HID * IN_DIM) / 256), dim3(256), 0, stream,
                       W, wt);
    hipLaunchKernelGGL(gemm_kernel, dim3((N_NODES + 127) / 128), dim3(256), 0, stream,
                       x, wt, h);
    hipLaunchKernelGGL(att_kernel, dim3((N_NODES + 3) / 4), dim3(256), 0, stream,
                       h, att_s, att_d, a_src, a_dst);
    hipLaunchKernelGGL(hist_kernel, dim3((N_EDGES + 255) / 256), dim3(256), 0, stream,
                       ei, deg);
    hipLaunchKernelGGL(scan1_kernel, dim3(NB), dim3(256), 0, stream, deg, bsum);
    hipLaunchKernelGGL(scan2_kernel, dim3(1), dim3(64), 0, stream, bsum, boff, rowstart, NB);
    hipLaunchKernelGGL(scan3_kernel, dim3(NB), dim3(256), 0, stream, deg, boff, rowstart);
    hipLaunchKernelGGL(scatter_kernel, dim3((N_EDGES + 255) / 256), dim3(256), 0, stream,
                       ei, rowstart, deg, csr);
    hipLaunchKernelGGL(aggregate_kernel, dim3((N_NODES + 3) / 4), dim3(256), 0, stream,
                       h, a_src, a_dst, rowstart, csr, bias, batch, out);
}

// Round 3
// 700.822 us; speedup vs baseline: 1.2178x; 1.0412x over previous
//
#include <hip/hip_runtime.h>
#include <hip/hip_bf16.h>

#define N_NODES 50000
#define N_EDGES 1600000
#define IN_DIM 1024
#define HID 128

typedef __bf16 bf16x8 __attribute__((ext_vector_type(8)));
typedef float f32x4 __attribute__((ext_vector_type(4)));
typedef __bf16 bf16x4 __attribute__((ext_vector_type(4)));

// bf16-pair (packed in uint) -> 2 floats
__device__ __forceinline__ float2 bf2f(unsigned u) {
    return make_float2(__uint_as_float(u << 16), __uint_as_float(u & 0xffff0000u));
}

// ---------------------------------------------------------------- init
__global__ void init_kernel(int* __restrict__ deg, float* __restrict__ out, int out_n) {
    int i = blockIdx.x * 256 + threadIdx.x;
    if (i < N_NODES) deg[i] = 0;
    if (i < out_n) out[i] = 0.0f;
}

// ---------------------------------------------------------------- W^T -> bf16  (wt[n][k], 128x1024)
__global__ void wtrans_kernel(const float* __restrict__ W, __bf16* __restrict__ wt) {
    int i = blockIdx.x * 256 + threadIdx.x;      // over 128*1024
    int n = i >> 10, k = i & 1023;
    wt[i] = (__bf16)W[(size_t)k * HID + n];
}

// ---------------------------------------------------------------- GEMM h = x @ W (bf16 MFMA)
// 128 rows/block x 128 cols (full HID). 4 waves, each 32 rows. BK=32, 16x16x32 bf16 MFMA.
// Epilogue writes h directly as bf16 (halves write traffic + downstream gather bytes).
__global__ __launch_bounds__(256) void gemm_kernel(const float* __restrict__ x,
                                                   const __bf16* __restrict__ wt,
                                                   __bf16* __restrict__ h2) {
    __shared__ __bf16 xa[128][40];
    __shared__ __bf16 wb[128][40];
    const int t = threadIdx.x;
    const int m0 = blockIdx.x * 128;
    const int wid = t >> 6, lane = t & 63;
    const int lm = lane & 15, q8 = (lane >> 4) * 8;
    const int rw0 = wid * 32;

    f32x4 acc[2][8] = {};
    for (int k0 = 0; k0 < IN_DIM; k0 += 32) {
#pragma unroll
        for (int l = 0; l < 4; ++l) {
            int f = t + l * 256;
            int row = f >> 3, kq = f & 7;       // kq -> k = kq*4
            int gr = m0 + row;
            float4 v = make_float4(0.f, 0.f, 0.f, 0.f);
            if (gr < N_NODES)
                v = *(const float4*)(x + (size_t)gr * IN_DIM + k0 + kq * 4);
            bf16x4 b; b[0] = (__bf16)v.x; b[1] = (__bf16)v.y; b[2] = (__bf16)v.z; b[3] = (__bf16)v.w;
            *(bf16x4*)&xa[row][kq * 4] = b;
        }
#pragma unroll
        for (int l = 0; l < 4; ++l) {
            int f = t + l * 256;
            int n = f >> 3, c = f & 7;
            *(uint2*)&wb[n][c * 4] = *(const uint2*)(wt + (size_t)n * IN_DIM + k0 + c * 4);
        }
        __syncthreads();
        bf16x8 af0 = *(const bf16x8*)&xa[rw0 + lm][q8];
        bf16x8 af1 = *(const bf16x8*)&xa[rw0 + 16 + lm][q8];
#pragma unroll
        for (int ct = 0; ct < 8; ++ct) {
            bf16x8 bfr = *(const bf16x8*)&wb[ct * 16 + lm][q8];
            acc[0][ct] = __builtin_amdgcn_mfma_f32_16x16x32_bf16(af0, bfr, acc[0][ct], 0, 0, 0);
            acc[1][ct] = __builtin_amdgcn_mfma_f32_16x16x32_bf16(af1, bfr, acc[1][ct], 0, 0, 0);
        }
        __syncthreads();
    }
    // epilogue: C/D layout col=lane&15, row=(lane>>4)*4+reg ; store bf16
    const int quad = lane >> 4;
#pragma unroll
    for (int rt = 0; rt < 2; ++rt) {
#pragma unroll
        for (int reg = 0; reg < 4; ++reg) {
            int row = m0 + rw0 + rt * 16 + quad * 4 + reg;
            if (row < N_NODES) {
#pragma unroll
                for (int ct = 0; ct < 8; ++ct)
                    h2[(size_t)row * HID + ct * 16 + lm] = (__bf16)acc[rt][ct][reg];
            }
        }
    }
}

// ---------------------------------------------------------------- a_src/a_dst = h . att
__global__ void att_kernel(const __bf16* __restrict__ h2, const float* __restrict__ as,
                           const float* __restrict__ adv, float* __restrict__ o_s,
                           float* __restrict__ o_d) {
    int wid = threadIdx.x >> 6, lane = threadIdx.x & 63;
    int i = blockIdx.x * 4 + wid;
    if (i >= N_NODES) return;
    float h0 = (float)h2[(size_t)i * HID + lane];
    float h1 = (float)h2[(size_t)i * HID + 64 + lane];
    float ps = h0 * as[lane] + h1 * as[64 + lane];
    float pd = h0 * adv[lane] + h1 * adv[64 + lane];
    for (int o = 32; o; o >>= 1) {
        ps += __shfl_xor(ps, o);
        pd += __shfl_xor(pd, o);
    }
    if (lane == 0) { o_s[i] = ps; o_d[i] = pd; }
}

// ---------------------------------------------------------------- CSR build
__global__ void hist_kernel(const int* __restrict__ ei, int* __restrict__ deg) {
    int e = blockIdx.x * 256 + threadIdx.x;
    if (e < N_EDGES) atomicAdd(&deg[ei[N_EDGES + e]], 1);
}

__global__ void scan1_kernel(const int* __restrict__ deg, int* __restrict__ bsum) {
    int b = blockIdx.x, t = threadIdx.x;
    int base = b * 1024 + t * 4;
    int s = 0;
#pragma unroll
    for (int j = 0; j < 4; ++j) {
        int idx = base + j;
        if (idx < N_NODES) s += deg[idx];
    }
    for (int o = 32; o; o >>= 1) s += __shfl_xor(s, o);
    __shared__ int wsum[4];
    int lane = t & 63, w = t >> 6;
    if (lane == 0) wsum[w] = s;
    __syncthreads();
    if (t == 0) bsum[b] = wsum[0] + wsum[1] + wsum[2] + wsum[3];
}

__global__ void scan2_kernel(const int* __restrict__ bsum, int* __restrict__ boff,
                             int* __restrict__ rowstart, int nb) {
    if (threadIdx.x == 0 && blockIdx.x == 0) {
        int run = 0;
        for (int i = 0; i < nb; ++i) { boff[i] = run; run += bsum[i]; }
        rowstart[N_NODES] = run;
    }
}

__global__ void scan3_kernel(int* __restrict__ deg, const int* __restrict__ boff,
                             int* __restrict__ rowstart) {
    int b = blockIdx.x, t = threadIdx.x;
    int base = b * 1024 + t * 4;
    int v[4]; int s = 0;
#pragma unroll
    for (int j = 0; j < 4; ++j) {
        int idx = base + j;
        v[j] = (idx < N_NODES) ? deg[idx] : 0;
        s += v[j];
    }
    int lane = t & 63, w = t >> 6;
    int inc = s;
    for (int o = 1; o < 64; o <<= 1) {
        int u = __shfl_up(inc, o);
        if (lane >= o) inc += u;
    }
    __shared__ int wt[4];
    if (lane == 63) wt[w] = inc;
    __syncthreads();
    int woff = 0;
    for (int i = 0; i < w; ++i) woff += wt[i];
    int run = woff + inc - s + boff[b];
#pragma unroll
    for (int j = 0; j < 4; ++j) {
        int idx = base + j;
        if (idx < N_NODES) {
            rowstart[idx] = run;
            run += v[j];
            deg[idx] = 0;   // re-zero: reused as scatter cursor
        }
    }
}

__global__ void scatter_kernel(const int* __restrict__ ei, const int* __restrict__ rowstart,
                               int* __restrict__ cursor, int* __restrict__ csr) {
    int e = blockIdx.x * 256 + threadIdx.x;
    if (e >= N_EDGES) return;
    int s = ei[e], d = ei[N_EDGES + e];
    int pos = atomicAdd(&cursor[d], 1);
    csr[rowstart[d] + pos] = s;
}

// ---------------------------------------------------------------- softmax+aggregate+pool
// One wave per dst node, lane owns features {2*lane, 2*lane+1} as one packed bf16 pair (4B).
// No max-subtraction (logits bounded, fp32 exp safe). Edge loop unrolled x16 for MLP:
// 16 independent 256B row-gathers in flight per wave.
__device__ __forceinline__ float lrelu(float v) { return v > 0.f ? v : 0.2f * v; }

__global__ __launch_bounds__(256) void aggregate_kernel(
    const unsigned* __restrict__ h2u, const float* __restrict__ a_src,
    const float* __restrict__ a_dst, const int* __restrict__ rowstart,
    const int* __restrict__ csr, const float* __restrict__ bias,
    const int* __restrict__ batch, float* __restrict__ out) {
    int wid = threadIdx.x >> 6, lane = threadIdx.x & 63;
    int n = blockIdx.x * 4 + wid;
    if (n >= N_NODES) return;
    int rs = rowstart[n], re = rowstart[n + 1];
    float adn = a_dst[n];
    float pself = __expf(lrelu(a_src[n] + adn));
    float2 hv = bf2f(h2u[(size_t)n * 64 + lane]);
    float denom = pself;
    float2 acc = make_float2(pself * hv.x, pself * hv.y);
    int j = rs;
    for (; j + 16 <= re; j += 16) {
        int s[16];
#pragma unroll
        for (int i = 0; i < 16; ++i) s[i] = csr[j + i];
        float a[16];
#pragma unroll
        for (int i = 0; i < 16; ++i) a[i] = a_src[s[i]];
        unsigned u[16];
#pragma unroll
        for (int i = 0; i < 16; ++i) u[i] = h2u[(size_t)s[i] * 64 + lane];
#pragma unroll
        for (int i = 0; i < 16; ++i) {
            float p = __expf(lrelu(a[i] + adn));
            denom += p;
            float2 g = bf2f(u[i]);
            acc.x = fmaf(p, g.x, acc.x);
            acc.y = fmaf(p, g.y, acc.y);
        }
    }
    for (; j < re; ++j) {
        int s = csr[j];
        float p = __expf(lrelu(a_src[s] + adn));
        float2 g = bf2f(h2u[(size_t)s * 64 + lane]);
        denom += p;
        acc.x = fmaf(p, g.x, acc.x);
        acc.y = fmaf(p, g.y, acc.y);
    }
    float inv = 1.0f / denom;
    float o0 = fmaxf(acc.x * inv + bias[2 * lane], 0.0f);
    float o1 = fmaxf(acc.y * inv + bias[2 * lane + 1], 0.0f);
    int g = batch[n];
    unsigned* outp = (unsigned*)(out + (size_t)g * HID);
    atomicMax(&outp[2 * lane], __float_as_uint(o0));
    atomicMax(&outp[2 * lane + 1], __float_as_uint(o1));
}

// ---------------------------------------------------------------- launch
extern "C" void kernel_launch(void* const* d_in, const int* in_sizes, int n_in,
                              void* d_out, int out_size, void* d_ws, size_t ws_size,
                              hipStream_t stream) {
    const float* x     = (const float*)d_in[0];
    const float* W     = (const float*)d_in[1];
    const float* att_s = (const float*)d_in[2];
    const float* att_d = (const float*)d_in[3];
    const float* bias  = (const float*)d_in[4];
    const int*   ei    = (const int*)d_in[5];
    const int*   batch = (const int*)d_in[6];
    float*       out   = (float*)d_out;

    char* ws = (char*)d_ws;
    size_t off = 0;
    auto alloc = [&](size_t bytes) -> void* {
        void* p = ws + off;
        off += (bytes + 255) & ~(size_t)255;
        return p;
    };
    const int NB = (N_NODES + 1023) / 1024;   // 49
    __bf16* h2       = (__bf16*)alloc((size_t)N_NODES * HID * 2);
    __bf16* wt       = (__bf16*)alloc((size_t)HID * IN_DIM * 2);
    float*  a_src    = (float*)alloc((size_t)N_NODES * 4);
    float*  a_dst    = (float*)alloc((size_t)N_NODES * 4);
    int*    deg      = (int*)alloc((size_t)N_NODES * 4);
    int*    rowstart = (int*)alloc((size_t)(N_NODES + 1) * 4);
    int*    bsum     = (int*)alloc((size_t)NB * 4);
    int*    boff     = (int*)alloc((size_t)NB * 4);
    int*    csr      = (int*)alloc((size_t)N_EDGES * 4);
    (void)ws_size; (void)in_sizes; (void)n_in;

    int init_n = (N_NODES > out_size ? N_NODES : out_size);
    hipLaunchKernelGGL(init_kernel, dim3((init_n + 255) / 256), dim3(256), 0, stream,
                       deg, out, out_size);
    hipLaunchKernelGGL(wtrans_kernel, dim3((HID * IN_DIM) / 256), dim3(256), 0, stream,
                       W, wt);
    hipLaunchKernelGGL(gemm_kernel, dim3((N_NODES + 127) / 128), dim3(256), 0, stream,
                       x, wt, h2);
    hipLaunchKernelGGL(att_kernel, dim3((N_NODES + 3) / 4), dim3(256), 0, stream,
                       h2, att_s, att_d, a_src, a_dst);
    hipLaunchKernelGGL(hist_kernel, dim3((N_EDGES + 255) / 256), dim3(256), 0, stream,
                       ei, deg);
    hipLaunchKernelGGL(scan1_kernel, dim3(NB), dim3(256), 0, stream, deg, bsum);
    hipLaunchKernelGGL(scan2_kernel, dim3(1), dim3(64), 0, stream, bsum, boff, rowstart, NB);
    hipLaunchKernelGGL(scan3_kernel, dim3(NB), dim3(256), 0, stream, deg, boff, rowstart);
    hipLaunchKernelGGL(scatter_kernel, dim3((N_EDGES + 255) / 256), dim3(256), 0, stream,
                       ei, rowstart, deg, csr);
    hipLaunchKernelGGL(aggregate_kernel, dim3((N_NODES + 3) / 4), dim3(256), 0, stream,
                       (const unsigned*)h2, a_src, a_dst, rowstart, csr, bias, batch, out);
}

// Round 4
// 661.437 us; speedup vs baseline: 1.2903x; 1.0595x over previous
//
#include <hip/hip_runtime.h>
#include <hip/hip_bf16.h>

#define N_NODES 50000
#define N_EDGES 1600000
#define IN_DIM 1024
#define HID 128

typedef __bf16 bf16x8 __attribute__((ext_vector_type(8)));
typedef float f32x4 __attribute__((ext_vector_type(4)));
typedef __bf16 bf16x4 __attribute__((ext_vector_type(4)));

// bf16-pair (packed in uint) -> 2 floats
__device__ __forceinline__ float2 bf2f(unsigned u) {
    return make_float2(__uint_as_float(u << 16), __uint_as_float(u & 0xffff0000u));
}
__device__ __forceinline__ float lrelu(float v) { return v > 0.f ? v : 0.2f * v; }

// ---------------------------------------------------------------- init
__global__ void init_kernel(int* __restrict__ deg, float* __restrict__ out, int out_n) {
    int i = blockIdx.x * 256 + threadIdx.x;
    if (i < N_NODES) deg[i] = 0;
    if (i < out_n) out[i] = 0.0f;
}

// ---------------------------------------------------------------- W^T -> bf16  (wt[n][k], 128x1024)
__global__ void wtrans_kernel(const float* __restrict__ W, __bf16* __restrict__ wt) {
    int i = blockIdx.x * 256 + threadIdx.x;      // over 128*1024
    int n = i >> 10, k = i & 1023;
    wt[i] = (__bf16)W[(size_t)k * HID + n];
}

// ---------------------------------------------------------------- GEMM h = x @ W (bf16 MFMA)
__global__ __launch_bounds__(256) void gemm_kernel(const float* __restrict__ x,
                                                   const __bf16* __restrict__ wt,
                                                   __bf16* __restrict__ h2) {
    __shared__ __bf16 xa[128][40];
    __shared__ __bf16 wb[128][40];
    const int t = threadIdx.x;
    const int m0 = blockIdx.x * 128;
    const int wid = t >> 6, lane = t & 63;
    const int lm = lane & 15, q8 = (lane >> 4) * 8;
    const int rw0 = wid * 32;

    f32x4 acc[2][8] = {};
    for (int k0 = 0; k0 < IN_DIM; k0 += 32) {
#pragma unroll
        for (int l = 0; l < 4; ++l) {
            int f = t + l * 256;
            int row = f >> 3, kq = f & 7;
            int gr = m0 + row;
            float4 v = make_float4(0.f, 0.f, 0.f, 0.f);
            if (gr < N_NODES)
                v = *(const float4*)(x + (size_t)gr * IN_DIM + k0 + kq * 4);
            bf16x4 b; b[0] = (__bf16)v.x; b[1] = (__bf16)v.y; b[2] = (__bf16)v.z; b[3] = (__bf16)v.w;
            *(bf16x4*)&xa[row][kq * 4] = b;
        }
#pragma unroll
        for (int l = 0; l < 4; ++l) {
            int f = t + l * 256;
            int n = f >> 3, c = f & 7;
            *(uint2*)&wb[n][c * 4] = *(const uint2*)(wt + (size_t)n * IN_DIM + k0 + c * 4);
        }
        __syncthreads();
        bf16x8 af0 = *(const bf16x8*)&xa[rw0 + lm][q8];
        bf16x8 af1 = *(const bf16x8*)&xa[rw0 + 16 + lm][q8];
#pragma unroll
        for (int ct = 0; ct < 8; ++ct) {
            bf16x8 bfr = *(const bf16x8*)&wb[ct * 16 + lm][q8];
            acc[0][ct] = __builtin_amdgcn_mfma_f32_16x16x32_bf16(af0, bfr, acc[0][ct], 0, 0, 0);
            acc[1][ct] = __builtin_amdgcn_mfma_f32_16x16x32_bf16(af1, bfr, acc[1][ct], 0, 0, 0);
        }
        __syncthreads();
    }
    const int quad = lane >> 4;
#pragma unroll
    for (int rt = 0; rt < 2; ++rt) {
#pragma unroll
        for (int reg = 0; reg < 4; ++reg) {
            int row = m0 + rw0 + rt * 16 + quad * 4 + reg;
            if (row < N_NODES) {
#pragma unroll
                for (int ct = 0; ct < 8; ++ct)
                    h2[(size_t)row * HID + ct * 16 + lm] = (__bf16)acc[rt][ct][reg];
            }
        }
    }
}

// ---------------------------------------------------------------- a_src/a_dst = h . att
__global__ void att_kernel(const __bf16* __restrict__ h2, const float* __restrict__ as,
                           const float* __restrict__ adv, float* __restrict__ o_s,
                           float* __restrict__ o_d) {
    int wid = threadIdx.x >> 6, lane = threadIdx.x & 63;
    int i = blockIdx.x * 4 + wid;
    if (i >= N_NODES) return;
    float h0 = (float)h2[(size_t)i * HID + lane];
    float h1 = (float)h2[(size_t)i * HID + 64 + lane];
    float ps = h0 * as[lane] + h1 * as[64 + lane];
    float pd = h0 * adv[lane] + h1 * adv[64 + lane];
    for (int o = 32; o; o >>= 1) {
        ps += __shfl_xor(ps, o);
        pd += __shfl_xor(pd, o);
    }
    if (lane == 0) { o_s[i] = ps; o_d[i] = pd; }
}

// ---------------------------------------------------------------- CSR build
__global__ void hist_kernel(const int* __restrict__ ei, int* __restrict__ deg) {
    int e = blockIdx.x * 256 + threadIdx.x;
    if (e < N_EDGES) atomicAdd(&deg[ei[N_EDGES + e]], 1);
}

__global__ void scan1_kernel(const int* __restrict__ deg, int* __restrict__ bsum) {
    int b = blockIdx.x, t = threadIdx.x;
    int base = b * 1024 + t * 4;
    int s = 0;
#pragma unroll
    for (int j = 0; j < 4; ++j) {
        int idx = base + j;
        if (idx < N_NODES) s += deg[idx];
    }
    for (int o = 32; o; o >>= 1) s += __shfl_xor(s, o);
    __shared__ int wsum[4];
    int lane = t & 63, w = t >> 6;
    if (lane == 0) wsum[w] = s;
    __syncthreads();
    if (t == 0) bsum[b] = wsum[0] + wsum[1] + wsum[2] + wsum[3];
}

__global__ void scan2_kernel(const int* __restrict__ bsum, int* __restrict__ boff,
                             int* __restrict__ rowstart, int nb) {
    if (threadIdx.x == 0 && blockIdx.x == 0) {
        int run = 0;
        for (int i = 0; i < nb; ++i) { boff[i] = run; run += bsum[i]; }
        rowstart[N_NODES] = run;
    }
}

__global__ void scan3_kernel(int* __restrict__ deg, const int* __restrict__ boff,
                             int* __restrict__ rowstart) {
    int b = blockIdx.x, t = threadIdx.x;
    int base = b * 1024 + t * 4;
    int v[4]; int s = 0;
#pragma unroll
    for (int j = 0; j < 4; ++j) {
        int idx = base + j;
        v[j] = (idx < N_NODES) ? deg[idx] : 0;
        s += v[j];
    }
    int lane = t & 63, w = t >> 6;
    int inc = s;
    for (int o = 1; o < 64; o <<= 1) {
        int u = __shfl_up(inc, o);
        if (lane >= o) inc += u;
    }
    __shared__ int wt[4];
    if (lane == 63) wt[w] = inc;
    __syncthreads();
    int woff = 0;
    for (int i = 0; i < w; ++i) woff += wt[i];
    int run = woff + inc - s + boff[b];
#pragma unroll
    for (int j = 0; j < 4; ++j) {
        int idx = base + j;
        if (idx < N_NODES) {
            rowstart[idx] = run;
            run += v[j];
            deg[idx] = 0;   // re-zero: reused as scatter cursor
        }
    }
}

// scatter + per-edge attention weight p = exp(lrelu(a_src[s]+a_dst[d])).
// Edge-parallel: the a_src/a_dst gathers here are latency-tolerant (1.6M threads).
__global__ void scatter_kernel(const int* __restrict__ ei, const int* __restrict__ rowstart,
                               int* __restrict__ cursor, uint2* __restrict__ csrp,
                               const float* __restrict__ a_src, const float* __restrict__ a_dst) {
    int e = blockIdx.x * 256 + threadIdx.x;
    if (e >= N_EDGES) return;
    int s = ei[e], d = ei[N_EDGES + e];
    int pos = atomicAdd(&cursor[d], 1);
    float p = __expf(lrelu(a_src[s] + a_dst[d]));
    uint2 v; v.x = (unsigned)s; v.y = __float_as_uint(p);
    csrp[rowstart[d] + pos] = v;
}

// ---------------------------------------------------------------- aggregate+pool
// One wave per dst node; lane owns features {2*lane,2*lane+1} (packed bf16 pair).
// Edge block of 64: lane e loads (src,p) coalesced; inner chunks of 16 broadcast
// (src,p) via shfl -> gather addresses are pure-register -> 16 gathers in flight.
__global__ __launch_bounds__(256) void aggregate_kernel(
    const unsigned* __restrict__ h2u, const float* __restrict__ a_src,
    const float* __restrict__ a_dst, const int* __restrict__ rowstart,
    const uint2* __restrict__ csrp, const float* __restrict__ bias,
    const int* __restrict__ batch, float* __restrict__ out) {
    int wid = threadIdx.x >> 6, lane = threadIdx.x & 63;
    int n = blockIdx.x * 4 + wid;
    if (n >= N_NODES) return;
    int rs = rowstart[n], re = rowstart[n + 1];
    float pself = __expf(lrelu(a_src[n] + a_dst[n]));
    float2 hv = bf2f(h2u[(size_t)n * 64 + lane]);
    float denom = pself;
    float2 acc = make_float2(pself * hv.x, pself * hv.y);
    for (int base = rs; base < re; base += 64) {
        int cnt = re - base; if (cnt > 64) cnt = 64;
        uint2 sp = make_uint2(0u, 0u);
        if (base + lane < re) sp = csrp[base + lane];
        float pe = __uint_as_float(sp.y);
        float ds = pe;
        for (int o = 32; o; o >>= 1) ds += __shfl_xor(ds, o);
        denom += ds;
        int e = 0;
        for (; e + 16 <= cnt; e += 16) {
            unsigned uu[16]; float pp[16];
#pragma unroll
            for (int i = 0; i < 16; ++i) {
                unsigned src = (unsigned)__shfl((int)sp.x, e + i);
                pp[i] = __shfl(pe, e + i);
                uu[i] = h2u[(size_t)src * 64 + lane];
            }
#pragma unroll
            for (int i = 0; i < 16; ++i) {
                float2 g = bf2f(uu[i]);
                acc.x = fmaf(pp[i], g.x, acc.x);
                acc.y = fmaf(pp[i], g.y, acc.y);
            }
        }
        unsigned uu2[8]; float pp2[8];
        int rem = cnt - e;
#pragma unroll
        for (int i = 0; i < 8; ++i) {
            if (i < rem) {
                unsigned src = (unsigned)__shfl((int)sp.x, e + i);
                pp2[i] = __shfl(pe, e + i);
                uu2[i] = h2u[(size_t)src * 64 + lane];
            }
        }
#pragma unroll
        for (int i = 0; i < 8; ++i) {
            if (i < rem) {
                float2 g = bf2f(uu2[i]);
                acc.x = fmaf(pp2[i], g.x, acc.x);
                acc.y = fmaf(pp2[i], g.y, acc.y);
            }
        }
        for (e += 8; e < cnt; ++e) {
            unsigned src = (unsigned)__shfl((int)sp.x, e);
            float p = __shfl(pe, e);
            float2 g = bf2f(h2u[(size_t)src * 64 + lane]);
            acc.x = fmaf(p, g.x, acc.x);
            acc.y = fmaf(p, g.y, acc.y);
        }
    }
    float inv = 1.0f / denom;
    float o0 = fmaxf(acc.x * inv + bias[2 * lane], 0.0f);
    float o1 = fmaxf(acc.y * inv + bias[2 * lane + 1], 0.0f);
    int g = batch[n];
    unsigned* outp = (unsigned*)(out + (size_t)g * HID);
    atomicMax(&outp[2 * lane], __float_as_uint(o0));
    atomicMax(&outp[2 * lane + 1], __float_as_uint(o1));
}

// ---------------------------------------------------------------- launch
extern "C" void kernel_launch(void* const* d_in, const int* in_sizes, int n_in,
                              void* d_out, int out_size, void* d_ws, size_t ws_size,
                              hipStream_t stream) {
    const float* x     = (const float*)d_in[0];
    const float* W     = (const float*)d_in[1];
    const float* att_s = (const float*)d_in[2];
    const float* att_d = (const float*)d_in[3];
    const float* bias  = (const float*)d_in[4];
    const int*   ei    = (const int*)d_in[5];
    const int*   batch = (const int*)d_in[6];
    float*       out   = (float*)d_out;

    char* ws = (char*)d_ws;
    size_t off = 0;
    auto alloc = [&](size_t bytes) -> void* {
        void* p = ws + off;
        off += (bytes + 255) & ~(size_t)255;
        return p;
    };
    const int NB = (N_NODES + 1023) / 1024;   // 49
    __bf16* h2       = (__bf16*)alloc((size_t)N_NODES * HID * 2);
    __bf16* wt       = (__bf16*)alloc((size_t)HID * IN_DIM * 2);
    float*  a_src    = (float*)alloc((size_t)N_NODES * 4);
    float*  a_dst    = (float*)alloc((size_t)N_NODES * 4);
    int*    deg      = (int*)alloc((size_t)N_NODES * 4);
    int*    rowstart = (int*)alloc((size_t)(N_NODES + 1) * 4);
    int*    bsum     = (int*)alloc((size_t)NB * 4);
    int*    boff     = (int*)alloc((size_t)NB * 4);
    uint2*  csrp     = (uint2*)alloc((size_t)N_EDGES * 8);
    (void)ws_size; (void)in_sizes; (void)n_in;

    int init_n = (N_NODES > out_size ? N_NODES : out_size);
    hipLaunchKernelGGL(init_kernel, dim3((init_n + 255) / 256), dim3(256), 0, stream,
                       deg, out, out_size);
    hipLaunchKernelGGL(wtrans_kernel, dim3((HID * IN_DIM) / 256), dim3(256), 0, stream,
                       W, wt);
    hipLaunchKernelGGL(gemm_kernel, dim3((N_NODES + 127) / 128), dim3(256), 0, stream,
                       x, wt, h2);
    hipLaunchKernelGGL(att_kernel, dim3((N_NODES + 3) / 4), dim3(256), 0, stream,
                       h2, att_s, att_d, a_src, a_dst);
    hipLaunchKernelGGL(hist_kernel, dim3((N_EDGES + 255) / 256), dim3(256), 0, stream,
                       ei, deg);
    hipLaunchKernelGGL(scan1_kernel, dim3(NB), dim3(256), 0, stream, deg, bsum);
    hipLaunchKernelGGL(scan2_kernel, dim3(1), dim3(64), 0, stream, bsum, boff, rowstart, NB);
    hipLaunchKernelGGL(scan3_kernel, dim3(NB), dim3(256), 0, stream, deg, boff, rowstart);
    hipLaunchKernelGGL(scatter_kernel, dim3((N_EDGES + 255) / 256), dim3(256), 0, stream,
                       ei, rowstart, deg, csrp, a_src, a_dst);
    hipLaunchKernelGGL(aggregate_kernel, dim3((N_NODES + 3) / 4), dim3(256), 0, stream,
                       (const unsigned*)h2, a_src, a_dst, rowstart, csrp, bias, batch, out);
}